// Round 9
// baseline (234.699 us; speedup 1.0000x reference)
//
#include <hip/hip_runtime.h>
#include <cstdint>
#include <cstddef>

typedef __attribute__((ext_vector_type(8))) short bf16x8;
typedef __attribute__((ext_vector_type(4))) float f32x4;

#define LOG2E 1.44269504f

__device__ __forceinline__ unsigned short f2bf(float x) {
  unsigned int u = __float_as_uint(x);
  u += 0x7FFFu + ((u >> 16) & 1u);   // RNE
  return (unsigned short)(u >> 16);
}
__device__ __forceinline__ unsigned short f2bf_trunc(float x) {
  return (unsigned short)(__float_as_uint(x) >> 16);
}

__device__ __forceinline__ bf16x8 pack8(const float4& a, const float4& b) {
  bf16x8 r;
  r[0] = (short)f2bf(a.x); r[1] = (short)f2bf(a.y);
  r[2] = (short)f2bf(a.z); r[3] = (short)f2bf(a.w);
  r[4] = (short)f2bf(b.x); r[5] = (short)f2bf(b.y);
  r[6] = (short)f2bf(b.z); r[7] = (short)f2bf(b.w);
  return r;
}

__device__ __forceinline__ bf16x8 packcol(const float* v) {
  bf16x8 r;
#pragma unroll
  for (int j = 0; j < 8; ++j) r[j] = (short)f2bf(v[j]);
  return r;
}

__device__ __forceinline__ void gload_lds16(const void* g, void* l) {
  __builtin_amdgcn_global_load_lds(
      (const __attribute__((address_space(1))) unsigned int*)g,
      (__attribute__((address_space(3))) unsigned int*)l, 16, 0, 0);
}

// ================= K1: qkv_direct — qkv from RAW fp32 inputs + aux jobs =================
// 2832 blocks x 256 thr, no grid barrier, no co-residency assumption.
//   bid <  768 : qkv job (128^2 tile, reg-staged ring-3, r5-verified skeleton).
//                A = fp32 X rows, cast in-flight (r5-proven).  B = fp32 W columns,
//                transposed in-flight: 16 coalesced scalar loads (column n=t&127,
//                k-half kg=t>>7) -> pack -> 2 ds_write_b128 at swizzled chunks.
//                Swizzle key(n) = ((n>>1)&3)^(((n>>3)&1)<<1)^((n>>4)&3): write-side
//                bank-optimal (exactly 2 granules/bank); read key = base(c)^jj.
//   768<=bid<2816 : Wg transpose tile job (verbatim old preproc z=2) -> bWgT.
//   2816<=bid<2832: bias table head h = bid-2816 -> biasT.

__global__ __launch_bounds__(256)
void qkv_direct(const float* __restrict__ x_q, const float* __restrict__ x_kv,
                const float* __restrict__ Wq, const float* __restrict__ Wm,
                const float* __restrict__ Wg,
                const float* __restrict__ amp, const float* __restrict__ off,
                const float* __restrict__ sharp,
                unsigned short* __restrict__ bWgT, float* __restrict__ biasT,
                unsigned short* __restrict__ qbuf, unsigned short* __restrict__ kbuf,
                unsigned short* __restrict__ vtbuf) {
  __shared__ __align__(16) char smem[49152];   // qkv: sA 24KB + sB 24KB; aux: [32][33] f32
  const int bid = blockIdx.x;
  const int t = threadIdx.x;

  if (bid >= 768) {
    if (bid < 2816) {
      // ---- Wg transpose tile (verbatim old preproc z=2) ----
      float* tile = (float*)smem;   // [32][33]
      const int idx = bid - 768;
      const int bx = idx & 63, by = idx >> 6;
      const int nb = bx * 32, kb = by * 32;
      const int tx = t & 31, ty = t >> 5;
#pragma unroll
      for (int r = ty; r < 32; r += 8)
        tile[r * 33 + tx] = Wg[(size_t)(kb + r) * 2048 + nb + tx];
      __syncthreads();
#pragma unroll
      for (int r = ty; r < 32; r += 8)
        bWgT[(size_t)(nb + r) * 1024 + kb + tx] = f2bf(tile[tx * 33 + r]);
    } else {
      // ---- bias table ----
      const int h = bid - 2816;
      for (int idx = t; idx < 2047; idx += 256) {
        float d = (float)(idx - 1023);
        float acc = 0.f;
#pragma unroll
        for (int k = 0; k < 21; ++k) {
          float dd = d - off[h * 21 + k];
          acc += amp[h * 21 + k] * __expf(-fabsf(sharp[h * 21 + k]) * dd * dd);
        }
        biasT[h * 2047 + idx] = acc * LOG2E;
      }
    }
    return;
  }

  // ---- qkv job ----
  unsigned short* sA = (unsigned short*)smem;            // 3 slots x 4096 ushorts
  unsigned short* sB = (unsigned short*)(smem + 24576);  // 3 slots x 4096 ushorts
  const int jid = bid;
  const bool isQ = jid < 256;
  const int jr = isQ ? jid : jid - 256;
  const int mt = jr & 31;           // mt fastest -> XCD A-locality (r0 pattern)
  const int nt = jr >> 5;           // Q: 0..7, KV: 0..15
  const int mtile = mt << 7, ntile = nt << 7;
  const float* X = isQ ? x_q : x_kv;
  const float* W = isQ ? Wq : Wm;
  const int N = isQ ? 1024 : 2048;

  const int lane = t & 63, w = t >> 6;
  const int wm = w >> 1, wn = w & 1;       // wave sub-tile 64x64
  const int c = lane & 15, g = lane >> 4;

  // A staging (r5-verified): rows sr and sr+64, pre-swizzled global chunk
  const int sr = t >> 2;
  const int sch = (t & 3) ^ ((sr >> 1) & 3);
  const float* aP0 = X + (size_t)(mtile + sr) * 1024 + sch * 8;
  const float* aP1 = aP0 + 64 * 1024;
  const int lw = t * 8;

  // B staging (new): column bn = t&127, k-half bkg = t>>7
  const int bn = t & 127, bkg = t >> 7;
  const float* bP = W + (size_t)(bkg * 16) * N + ntile + bn;
  const int bkey = ((bn >> 1) & 3) ^ (((bn >> 3) & 1) << 1) ^ ((bn >> 4) & 3);
  const int bw0 = bn * 32 + (((bkg * 2) ^ bkey) * 8);      // phys slot for lc = 2*bkg
  const int bw1 = bn * 32 + (((bkg * 2 + 1) ^ bkey) * 8);  // phys slot for lc = 2*bkg+1

  // ---- prologue: tile0 -> slot0; tile1 pending in regs ----
  float4 pA[4], iA[4];
  float pBv[16], iBv[16];
  {
    float4 c0 = *(const float4*)(aP0);
    float4 c1 = *(const float4*)(aP0 + 4);
    float4 c2 = *(const float4*)(aP1);
    float4 c3 = *(const float4*)(aP1 + 4);
    float cb[16];
#pragma unroll
    for (int i = 0; i < 16; ++i) cb[i] = bP[(size_t)i * N];
    pA[0] = *(const float4*)(aP0 + 32);
    pA[1] = *(const float4*)(aP0 + 36);
    pA[2] = *(const float4*)(aP1 + 32);
    pA[3] = *(const float4*)(aP1 + 36);
#pragma unroll
    for (int i = 0; i < 16; ++i) pBv[i] = bP[(size_t)(32 + i) * N];
    *(bf16x8*)&sA[lw]        = pack8(c0, c1);
    *(bf16x8*)&sA[2048 + lw] = pack8(c2, c3);
    *(bf16x8*)&sB[bw0] = packcol(cb);
    *(bf16x8*)&sB[bw1] = packcol(cb + 8);
  }
  asm volatile("s_waitcnt lgkmcnt(0)" ::: "memory");
  __builtin_amdgcn_sched_barrier(0);
  asm volatile("s_barrier" ::: "memory");

  const int gxA = (g ^ ((c >> 1) & 3)) * 8;
  const int aoff = (wm * 64 + c) * 32 + gxA;
  const int kbse = ((c >> 1) & 3) ^ ((c >> 3) << 1);
  const int brow = (wn * 64 + c) * 32;

  f32x4 acc[4][4] = {};
  int s0 = 0, s1 = 4096, s2 = 8192;

  for (int kt = 0; kt < 32; ++kt) {
    // issue loads for tile kt+2 (stay in flight across this tile)
    if (kt + 2 < 32) {
      const int ko = (kt + 2) * 32;
      iA[0] = *(const float4*)(aP0 + ko);
      iA[1] = *(const float4*)(aP0 + ko + 4);
      iA[2] = *(const float4*)(aP1 + ko);
      iA[3] = *(const float4*)(aP1 + ko + 4);
#pragma unroll
      for (int i = 0; i < 16; ++i) iBv[i] = bP[(size_t)(ko + i) * N];
    }

    const unsigned short* sAp = &sA[s0];
    const unsigned short* sBc = &sB[s0];
    bf16x8 af[4], bfr[4];
#pragma unroll
    for (int i = 0; i < 4; ++i) af[i] = *(const bf16x8*)&sAp[aoff + i * 512];
#pragma unroll
    for (int jj = 0; jj < 4; ++jj)
      bfr[jj] = *(const bf16x8*)&sBc[brow + jj * 512 + ((g ^ kbse ^ jj) * 8)];

    __builtin_amdgcn_s_setprio(1);
#pragma unroll
    for (int i = 0; i < 4; ++i)
#pragma unroll
      for (int j = 0; j < 4; ++j)
        acc[i][j] = __builtin_amdgcn_mfma_f32_16x16x32_bf16(af[i], bfr[j], acc[i][j], 0, 0, 0);
    __builtin_amdgcn_s_setprio(0);

    // commit tile kt+1 (regs loaded during tile kt-1); counted vmcnt inserted here
    if (kt + 1 < 32) {
      *(bf16x8*)&sA[s1 + lw]        = pack8(pA[0], pA[1]);
      *(bf16x8*)&sA[s1 + 2048 + lw] = pack8(pA[2], pA[3]);
      *(bf16x8*)&sB[s1 + bw0] = packcol(pBv);
      *(bf16x8*)&sB[s1 + bw1] = packcol(pBv + 8);
    }
#pragma unroll
    for (int q = 0; q < 4; ++q) pA[q] = iA[q];
#pragma unroll
    for (int q = 0; q < 16; ++q) pBv[q] = iBv[q];

    asm volatile("s_waitcnt lgkmcnt(0)" ::: "memory");
    __builtin_amdgcn_sched_barrier(0);
    asm volatile("s_barrier" ::: "memory");
    __builtin_amdgcn_sched_barrier(0);

    int tmp = s0; s0 = s1; s1 = s2; s2 = tmp;
  }

  const int row0 = mtile + wm * 64 + (g << 2);
  const int col0 = ntile + wn * 64 + c;
  if (isQ) {
#pragma unroll
    for (int i = 0; i < 4; ++i)
#pragma unroll
      for (int j = 0; j < 4; ++j) {
        int r = row0 + i * 16, cl = col0 + j * 16;
#pragma unroll
        for (int ri = 0; ri < 4; ++ri)
          qbuf[(size_t)(r + ri) * 1024 + cl] = f2bf(acc[i][j][ri] * (0.125f * LOG2E));
      }
  } else if (ntile < 1024) {   // K tile (block-uniform)
#pragma unroll
    for (int i = 0; i < 4; ++i)
#pragma unroll
      for (int j = 0; j < 4; ++j) {
        int r = row0 + i * 16, cl = col0 + j * 16;
#pragma unroll
        for (int ri = 0; ri < 4; ++ri)
          kbuf[(size_t)(r + ri) * 1024 + cl] = f2bf(acc[i][j][ri]);
      }
  } else {                     // V tile -> transposed pack
#pragma unroll
    for (int i = 0; i < 4; ++i)
#pragma unroll
      for (int j = 0; j < 4; ++j) {
        int r = row0 + i * 16, cl = col0 + j * 16;
        int d = cl - 1024;
        int hh = d >> 6, dh = d & 63;
        int bb2 = r >> 10, ll = r & 1023;
        ushort4 pk;
        pk.x = f2bf(acc[i][j][0]);
        pk.y = f2bf(acc[i][j][1]);
        pk.z = f2bf(acc[i][j][2]);
        pk.w = f2bf(acc[i][j][3]);
        *(ushort4*)&vtbuf[((size_t)((bb2 * 16 + hh) * 64 + dh) << 10) + ll] = pk;
      }
  }
}

// ---------------- flash attention v7 (verbatim round-8) ----------------

__global__ __launch_bounds__(512)
void attn_kernel(const unsigned short* __restrict__ qbuf,
                 const unsigned short* __restrict__ kbuf,
                 const unsigned short* __restrict__ vtbuf,
                 const float* __restrict__ biasTab,
                 unsigned short* __restrict__ attnb) {
  const int h = blockIdx.x & 15, b = blockIdx.x >> 4, qt = blockIdx.y;
  __shared__ unsigned short sK[2][64 * 64];
  __shared__ unsigned short sV[3][64 * 64];
  __shared__ unsigned short sP[2][128 * 64];
  __shared__ float sLsum[2][128];
  const int t = threadIdx.x, lane = t & 63, w = t >> 6;
  const int c = lane & 15, g = lane >> 4;
  const int rg = w >> 1, cg = w & 1;

  const int r = t >> 3, ch = (t & 7) ^ (r & 7);

  const unsigned short* qsrc = qbuf + (size_t)(b * 1024 + qt * 128) * 1024 + h * 64;
  const unsigned short* ksrc = kbuf + (size_t)(b * 1024) * 1024 + h * 64;
  const unsigned short* vsrc = vtbuf + (size_t)((b * 16 + h) * 64) * 1024;

  unsigned short* sQ = &sP[0][0];
  gload_lds16(qsrc + (size_t)r * 1024 + ch * 8, &sQ[t * 8]);
  gload_lds16(qsrc + (size_t)(r + 64) * 1024 + ch * 8, &sQ[4096 + t * 8]);
  gload_lds16(ksrc + (size_t)r * 1024 + ch * 8, &sK[0][t * 8]);
  gload_lds16(vsrc + (size_t)r * 1024 + ch * 8, &sV[0][t * 8]);

  const float* bb = biasTab + h * 2047 + 1023 + cg * 32 + c - qt * 128 - rg * 32 - g * 4;

  float bc[2][2][4];
#pragma unroll
  for (int rf = 0; rf < 2; ++rf)
#pragma unroll
    for (int nf = 0; nf < 2; ++nf)
#pragma unroll
      for (int ri = 0; ri < 4; ++ri)
        bc[rf][nf][ri] = bb[(nf - rf) * 16 - ri];

  __syncthreads();

  bf16x8 aq[2][2];
#pragma unroll
  for (int rf = 0; rf < 2; ++rf) {
    int row = rg * 32 + rf * 16 + c;
#pragma unroll
    for (int ks = 0; ks < 2; ++ks)
      aq[rf][ks] = *(const bf16x8*)&sQ[row * 64 + (((ks * 4 + g) ^ (row & 7)) * 8)];
  }
  __syncthreads();

  f32x4 o[2][2] = {};
  float lsum[2][4] = {};

  int vcur = 0, vnx = 1;
  for (int kv = 0; kv < 16; ++kv) {
    const int cur = kv & 1;

    f32x4 s[2][2];
#pragma unroll
    for (int rf = 0; rf < 2; ++rf)
#pragma unroll
      for (int nf = 0; nf < 2; ++nf)
#pragma unroll
        for (int ri = 0; ri < 4; ++ri)
          s[rf][nf][ri] = bc[rf][nf][ri];

    if (kv + 1 < 16) {
      gload_lds16(ksrc + (size_t)((kv + 1) * 64 + r) * 1024 + ch * 8, &sK[1 - cur][t * 8]);
      gload_lds16(vsrc + (size_t)r * 1024 + (kv + 1) * 64 + ch * 8, &sV[vnx][t * 8]);
      const float* bk = bb + (kv + 1) * 64;
#pragma unroll
      for (int rf = 0; rf < 2; ++rf)
#pragma unroll
        for (int nf = 0; nf < 2; ++nf)
#pragma unroll
          for (int ri = 0; ri < 4; ++ri)
            bc[rf][nf][ri] = bk[(nf - rf) * 16 - ri];
    }

#pragma unroll
    for (int nf = 0; nf < 2; ++nf) {
      int krow = cg * 32 + nf * 16 + c;
      bf16x8 k0 = *(const bf16x8*)&sK[cur][krow * 64 + (((g) ^ (krow & 7)) * 8)];
      bf16x8 k1 = *(const bf16x8*)&sK[cur][krow * 64 + (((4 + g) ^ (krow & 7)) * 8)];
#pragma unroll
      for (int rf = 0; rf < 2; ++rf) {
        s[rf][nf] = __builtin_amdgcn_mfma_f32_16x16x32_bf16(aq[rf][0], k0, s[rf][nf], 0, 0, 0);
        s[rf][nf] = __builtin_amdgcn_mfma_f32_16x16x32_bf16(aq[rf][1], k1, s[rf][nf], 0, 0, 0);
      }
    }

#pragma unroll
    for (int rf = 0; rf < 2; ++rf)
#pragma unroll
      for (int nf = 0; nf < 2; ++nf)
#pragma unroll
        for (int ri = 0; ri < 4; ++ri) {
          float e = exp2f(s[rf][nf][ri]);
          lsum[rf][ri] += e;
          int prow = rg * 32 + rf * 16 + g * 4 + ri;
          int chunk = cg * 4 + nf * 2 + (c >> 3);
          sP[cur][prow * 64 + ((chunk ^ (prow & 7)) * 8) + (c & 7)] = f2bf_trunc(e);
        }
    __syncthreads();

    bf16x8 ap[2][2];
#pragma unroll
    for (int rf = 0; rf < 2; ++rf) {
      int row = rg * 32 + rf * 16 + c;
#pragma unroll
      for (int ks = 0; ks < 2; ++ks)
        ap[rf][ks] = *(const bf16x8*)&sP[cur][row * 64 + (((ks * 4 + g) ^ (row & 7)) * 8)];
    }
#pragma unroll
    for (int df = 0; df < 2; ++df) {
      int vrow = cg * 32 + df * 16 + c;
      bf16x8 v0 = *(const bf16x8*)&sV[vcur][vrow * 64 + (((g) ^ (vrow & 7)) * 8)];
      bf16x8 v1 = *(const bf16x8*)&sV[vcur][vrow * 64 + (((4 + g) ^ (vrow & 7)) * 8)];
#pragma unroll
      for (int rf = 0; rf < 2; ++rf) {
        o[rf][df] = __builtin_amdgcn_mfma_f32_16x16x32_bf16(ap[rf][0], v0, o[rf][df], 0, 0, 0);
        o[rf][df] = __builtin_amdgcn_mfma_f32_16x16x32_bf16(ap[rf][1], v1, o[rf][df], 0, 0, 0);
      }
    }
    vcur = vnx;
    vnx = (vnx == 2) ? 0 : vnx + 1;
  }

#pragma unroll
  for (int off = 1; off < 16; off <<= 1)
#pragma unroll
    for (int rf = 0; rf < 2; ++rf)
#pragma unroll
      for (int ri = 0; ri < 4; ++ri)
        lsum[rf][ri] += __shfl_xor(lsum[rf][ri], off, 64);
  if (c == 0) {
#pragma unroll
    for (int rf = 0; rf < 2; ++rf)
#pragma unroll
      for (int ri = 0; ri < 4; ++ri)
        sLsum[cg][rg * 32 + rf * 16 + g * 4 + ri] = lsum[rf][ri];
  }
  __syncthreads();

  unsigned short* obase = attnb +
      (size_t)(b * 1024 + qt * 128 + rg * 32 + g * 4) * 1024 + h * 64 + cg * 32 + c;
#pragma unroll
  for (int rf = 0; rf < 2; ++rf)
#pragma unroll
    for (int ri = 0; ri < 4; ++ri) {
      int row = rg * 32 + rf * 16 + g * 4 + ri;
      float rinv = 1.0f / (sLsum[0][row] + sLsum[1][row]);
#pragma unroll
      for (int df = 0; df < 2; ++df)
        obase[(size_t)(rf * 16 + ri) * 1024 + df * 16] = f2bf(o[rf][df][ri] * rinv);
    }
}

// ---------------- output GEMM (verbatim round-8) ----------------

__global__ __launch_bounds__(256, 4)
void out_gemm(const unsigned short* __restrict__ A,
              const unsigned short* __restrict__ WgT,
              const float* __restrict__ bg,
              float* __restrict__ out) {
  __shared__ unsigned short sA[2][64 * 32];
  __shared__ unsigned short sB[2][128 * 32];
  const int nb = blockIdx.y;
  const int mtile = blockIdx.x << 6;
  const int t = threadIdx.x, lane = t & 63, w = t >> 6;
  const int c = lane & 15, g = lane >> 4;
  const int rm = w >> 1, cn = w & 1;
  const int srow = t >> 2, scol = (t & 3) << 3;
  const unsigned short* aP = A + (size_t)(mtile + srow) * 1024 + scol;
  const unsigned short* bP0 = WgT + (size_t)(nb * 64 + srow) * 1024 + scol;
  const unsigned short* bP1 = WgT + (size_t)(1024 + nb * 64 + srow) * 1024 + scol;
  const int lo = srow * 32 + scol;

  gload_lds16(aP, &sA[0][lo]);
  gload_lds16(bP0, &sB[0][lo]);
  gload_lds16(bP1, &sB[0][lo + 64 * 32]);
  __syncthreads();

  f32x4 acc[2][4] = {};
  for (int kt = 0; kt < 32; ++kt) {
    const int cur = kt & 1;
    if (kt + 1 < 32) {
      const int ko = (kt + 1) * 32;
      gload_lds16(aP + ko, &sA[1 - cur][lo]);
      gload_lds16(bP0 + ko, &sB[1 - cur][lo]);
      gload_lds16(bP1 + ko, &sB[1 - cur][lo + 64 * 32]);
    }
    bf16x8 af[2], bfr[4];
#pragma unroll
    for (int i = 0; i < 2; ++i)
      af[i] = *(const bf16x8*)&sA[cur][(rm * 32 + i * 16 + c) * 32 + g * 8];
#pragma unroll
    for (int jj = 0; jj < 2; ++jj) {
      bfr[jj]     = *(const bf16x8*)&sB[cur][(cn * 32 + jj * 16 + c) * 32 + g * 8];
      bfr[jj + 2] = *(const bf16x8*)&sB[cur][(64 + cn * 32 + jj * 16 + c) * 32 + g * 8];
    }
#pragma unroll
    for (int i = 0; i < 2; ++i)
#pragma unroll
      for (int j = 0; j < 4; ++j)
        acc[i][j] = __builtin_amdgcn_mfma_f32_16x16x32_bf16(af[i], bfr[j], acc[i][j], 0, 0, 0);
    __syncthreads();
  }

#pragma unroll
  for (int i = 0; i < 2; ++i) {
    int row0 = mtile + rm * 32 + i * 16 + (g << 2);
#pragma unroll
    for (int jj = 0; jj < 2; ++jj) {
      int col = nb * 64 + cn * 32 + jj * 16 + c;
      float ba = bg[col];
      float bbv = bg[1024 + col];
#pragma unroll
      for (int ri = 0; ri < 4; ++ri) {
        float av = acc[i][jj][ri] + ba;
        float bv = acc[i][jj + 2][ri] + bbv;
        out[(size_t)(row0 + ri) * 1024 + col] = av / (1.f + exp2f(-LOG2E * bv));
      }
    }
  }
}

// ---------------- launch: THREE dispatches ----------------

extern "C" void kernel_launch(void* const* d_in, const int* in_sizes, int n_in,
                              void* d_out, int out_size, void* d_ws, size_t ws_size,
                              hipStream_t stream) {
  const float* x_q   = (const float*)d_in[0];
  const float* x_kv  = (const float*)d_in[1];
  const float* Wq    = (const float*)d_in[2];
  const float* Wm    = (const float*)d_in[3];
  const float* Wg    = (const float*)d_in[4];
  const float* bg    = (const float*)d_in[5];
  const float* amp   = (const float*)d_in[6];
  const float* off   = (const float*)d_in[7];
  const float* sharp = (const float*)d_in[8];
  float* out = (float*)d_out;

  char* ws = (char*)d_ws;
  size_t o = 0;
  auto alloc = [&](size_t bytes) {
    char* p = ws + o;
    o += (bytes + 255) & ~(size_t)255;
    return p;
  };
  unsigned short* bWgT  = (unsigned short*)alloc(2048ull * 1024 * 2);
  float*          biasT = (float*)alloc(16ull * 2047 * 4);
  unsigned short* qbuf  = (unsigned short*)alloc(4096ull * 1024 * 2);
  unsigned short* kbuf  = (unsigned short*)alloc(4096ull * 1024 * 2);
  unsigned short* vtbuf = (unsigned short*)alloc(4096ull * 1024 * 2);
  unsigned short* attnb = (unsigned short*)alloc(4096ull * 1024 * 2);
  if (ws_size < o) return;

  qkv_direct<<<2832, 256, 0, stream>>>(x_q, x_kv, Wq, Wm, Wg, amp, off, sharp,
                                       bWgT, biasT, qbuf, kbuf, vtbuf);
  attn_kernel<<<dim3(64, 8), 512, 0, stream>>>(qbuf, kbuf, vtbuf, biasT, attnb);
  out_gemm<<<dim3(64, 16), 256, 0, stream>>>(attnb, bWgT, bg, out);
}